// Round 1
// baseline (1002.079 us; speedup 1.0000x reference)
//
#include <hip/hip_runtime.h>

typedef __attribute__((ext_vector_type(8))) short bf16x8;
typedef __attribute__((ext_vector_type(4))) float f32x4;
typedef __attribute__((ext_vector_type(8))) unsigned short u16x8;

#define BM 128
#define BN 128
#define BK 32
#define MDIM 4096
#define NDIM 11008
#define KDIM 4096
#define KP   (KDIM / 2)
#define NKT  (KDIM / BK)

__device__ __forceinline__ unsigned short f2bf(float f) {
  unsigned int u = __float_as_uint(f);
  u += 0x7FFFu + ((u >> 16) & 1u);   // round-to-nearest-even
  return (unsigned short)(u >> 16);
}

__global__ __launch_bounds__(256, 2)
void int4_linear_kernel(const float* __restrict__ X,
                        const int* __restrict__ Wp,
                        const float* __restrict__ scale,
                        const float* __restrict__ bias,
                        float* __restrict__ Out)
{
  // +8 shorts pad -> 80B row stride (20 banks): 16-lane frag reads are 2-way
  // bank-aliased (free, m136); keeps 16B alignment for b128 ops.
  __shared__ alignas(16) unsigned short As[2][BM][40];
  __shared__ alignas(16) unsigned short Bs[2][BN][40];

  const int t    = threadIdx.x;
  const int lane = t & 63;
  const int wid  = t >> 6;
  const int wm   = wid >> 1;   // wave row (0..1) -> 64 rows each
  const int wn   = wid & 1;    // wave col (0..1) -> 64 cols each
  const int lr   = lane & 15;
  const int kg   = lane >> 4;

  // XCD-aware bijective swizzle: 2752 blocks, 2752 % 8 == 0
  const int NWG = (MDIM / BM) * (NDIM / BN);     // 32 * 86 = 2752
  const int wg  = (blockIdx.x & 7) * (NWG >> 3) + (blockIdx.x >> 3);
  const int bm  = wg & 31;                        // MDIM/BM = 32 (fast axis)
  const int bn  = wg >> 5;
  const int row0 = bm * BM;
  const int col0 = bn * BN;

  // A staging: 8 threads/row * 4 passes; 128B contiguous per row (coalesced)
  const int arow = t >> 3;            // 0..31
  const int acol = (t & 7) << 2;      // float col 0..28
  // B staging: 2 threads/row; each loads 8 packed int32 (= 16 k-values)
  const int brow  = t >> 1;           // 0..127
  const int bhalf = t & 1;

  const float* Abase = X  + (size_t)(row0 + arow) * KDIM + acol;
  const int*   Bbase = Wp + (size_t)(col0 + brow) * KP + (bhalf << 3);

  float4 aR[4];
  int4   bR[2];

  f32x4 acc[4][4];
  #pragma unroll
  for (int i = 0; i < 4; ++i)
    #pragma unroll
    for (int j = 0; j < 4; ++j)
      #pragma unroll
      for (int e = 0; e < 4; ++e)
        acc[i][j][e] = 0.0f;

  auto loadG = [&](int kt) {
    const float* ap = Abase + kt * BK;
    #pragma unroll
    for (int p = 0; p < 4; ++p)
      aR[p] = *(const float4*)(ap + (size_t)p * 32 * KDIM);
    const int* bp = Bbase + kt * (BK / 2);
    bR[0] = *(const int4*)bp;
    bR[1] = *(const int4*)(bp + 4);
  };

  auto stageL = [&](int buf) {
    #pragma unroll
    for (int p = 0; p < 4; ++p) {
      ushort4 u;
      u.x = f2bf(aR[p].x);
      u.y = f2bf(aR[p].y);
      u.z = f2bf(aR[p].z);
      u.w = f2bf(aR[p].w);
      *(ushort4*)&As[buf][arow + p * 32][acol] = u;
    }
    #pragma unroll
    for (int q = 0; q < 2; ++q) {
      const int v0 = (q ? bR[1].x : bR[0].x);
      const int v1 = (q ? bR[1].y : bR[0].y);
      const int v2 = (q ? bR[1].z : bR[0].z);
      const int v3 = (q ? bR[1].w : bR[0].w);
      const int vv[4] = {v0, v1, v2, v3};
      u16x8 s;
      #pragma unroll
      for (int j = 0; j < 4; ++j) {
        const int lo = ((vv[j] & 15) ^ 8) - 8;          // sign-extend int4
        const int hi = (((vv[j] >> 4) & 15) ^ 8) - 8;
        s[2 * j]     = f2bf((float)lo);                  // even k
        s[2 * j + 1] = f2bf((float)hi);                  // odd k
      }
      *(u16x8*)&Bs[buf][brow][(bhalf << 4) + (q << 3)] = s;
    }
  };

  auto compute = [&](int buf) {
    bf16x8 a[4], b[4];
    #pragma unroll
    for (int mi = 0; mi < 4; ++mi)
      a[mi] = *(const bf16x8*)&As[buf][wm * 64 + mi * 16 + lr][kg * 8];
    #pragma unroll
    for (int ni = 0; ni < 4; ++ni)
      b[ni] = *(const bf16x8*)&Bs[buf][wn * 64 + ni * 16 + lr][kg * 8];
    #pragma unroll
    for (int mi = 0; mi < 4; ++mi)
      #pragma unroll
      for (int ni = 0; ni < 4; ++ni)
        acc[mi][ni] = __builtin_amdgcn_mfma_f32_16x16x32_bf16(
            a[mi], b[ni], acc[mi][ni], 0, 0, 0);
  };

  // prologue: stage K-tile 0
  loadG(0);
  stageL(0);
  __syncthreads();

  for (int kt = 0; kt < NKT; ++kt) {
    const int cur = kt & 1;
    if (kt + 1 < NKT) loadG(kt + 1);     // HBM loads in flight over MFMAs
    compute(cur);
    if (kt + 1 < NKT) stageL(cur ^ 1);   // convert + write other buffer
    __syncthreads();
  }

  // epilogue: D layout col = lane&15, row = (lane>>4)*4 + j (m89)
  #pragma unroll
  for (int ni = 0; ni < 4; ++ni) {
    const int n = col0 + wn * 64 + ni * 16 + lr;
    const float sc = scale[n];
    const float bz = bias[n];
    #pragma unroll
    for (int mi = 0; mi < 4; ++mi) {
      const int m0 = row0 + wm * 64 + mi * 16 + (kg << 2);
      #pragma unroll
      for (int j = 0; j < 4; ++j)
        Out[(size_t)(m0 + j) * NDIM + n] = acc[mi][ni][j] * sc + bz;
    }
  }
}

extern "C" void kernel_launch(void* const* d_in, const int* in_sizes, int n_in,
                              void* d_out, int out_size, void* d_ws, size_t ws_size,
                              hipStream_t stream) {
  const float* x     = (const float*)d_in[0];
  const int*   wp    = (const int*)d_in[1];
  const float* scale = (const float*)d_in[2];
  const float* bias  = (const float*)d_in[3];
  float* out = (float*)d_out;

  const int nwg = (MDIM / BM) * (NDIM / BN);   // 2752
  hipLaunchKernelGGL(int4_linear_kernel, dim3(nwg), dim3(256), 0, stream,
                     x, wp, scale, bias, out);
}

// Round 7
// 760.289 us; speedup vs baseline: 1.3180x; 1.3180x over previous
//
#include <hip/hip_runtime.h>

typedef __attribute__((ext_vector_type(8))) short bf16x8;
typedef __attribute__((ext_vector_type(4))) float f32x4;
typedef __attribute__((ext_vector_type(8))) unsigned short u16x8;

#define MDIM 4096
#define NDIM 11008
#define KDIM 4096
#define KP   (KDIM / 2)

__device__ __forceinline__ unsigned short f2bf(float f) {
  unsigned int u = __float_as_uint(f);
  u += 0x7FFFu + ((u >> 16) & 1u);   // round-to-nearest-even
  return (unsigned short)(u >> 16);
}

// ---------------- prep kernels (memory-bound, ~45 us total) ----------------

__global__ __launch_bounds__(256) void cvt_x_kernel(const float* __restrict__ X,
                                                    unsigned short* __restrict__ Xb) {
  const int stride = gridDim.x * blockDim.x;
  for (int i = blockIdx.x * blockDim.x + threadIdx.x; i < (MDIM * KDIM / 8); i += stride) {
    const float4 f0 = ((const float4*)X)[2 * i];
    const float4 f1 = ((const float4*)X)[2 * i + 1];
    ushort4 a, b;
    a.x = f2bf(f0.x); a.y = f2bf(f0.y); a.z = f2bf(f0.z); a.w = f2bf(f0.w);
    b.x = f2bf(f1.x); b.y = f2bf(f1.y); b.z = f2bf(f1.z); b.w = f2bf(f1.w);
    ((ushort4*)Xb)[2 * i]     = a;
    ((ushort4*)Xb)[2 * i + 1] = b;
  }
}

// Each int32 in [0,256) packs TWO int4: low nibble -> even k, high -> odd k.
__global__ __launch_bounds__(256) void unpack_w_kernel(const int* __restrict__ Wp,
                                                       unsigned short* __restrict__ Wb) {
  const int stride = gridDim.x * blockDim.x;
  const int n4 = NDIM * KP / 4;     // 5636096 int4-vectors  (R2 BUG: had /2/4)
  for (int i = blockIdx.x * blockDim.x + threadIdx.x; i < n4; i += stride) {
    const int4 v = ((const int4*)Wp)[i];
    const int vv[4] = {v.x, v.y, v.z, v.w};
    u16x8 s;
    #pragma unroll
    for (int j = 0; j < 4; ++j) {
      const int lo = ((vv[j] & 15) ^ 8) - 8;          // sign-extend int4 (exact in bf16)
      const int hi = (((vv[j] >> 4) & 15) ^ 8) - 8;
      s[2 * j]     = f2bf((float)lo);
      s[2 * j + 1] = f2bf((float)hi);
    }
    *(u16x8*)(Wb + 8 * (size_t)i) = s;
  }
}

// ---------------- main GEMM: m97 structure, global_load_lds both operands ----

#define GNWG ((MDIM / 128) * (NDIM / 128))   // 32 * 86 = 2752

__global__ __launch_bounds__(256, 2)
void gemm_bf16_kernel(const unsigned short* __restrict__ Xb,
                      const unsigned short* __restrict__ Wb,
                      const float* __restrict__ scale,
                      const float* __restrict__ bias,
                      float* __restrict__ Out) {
  // linear layout (global_load_lds requires contiguous dest); 32 KB total
  __shared__ alignas(16) unsigned short As[2][128 * 32];
  __shared__ alignas(16) unsigned short Bs[2][128 * 32];

  const int t    = threadIdx.x;
  const int lane = t & 63;
  const int wid  = t >> 6;
  const int wm   = wid >> 1;   // 2x2 wave grid, 64x64 per wave
  const int wn   = wid & 1;
  const int lr   = lane & 15;
  const int kg   = lane >> 4;

  // XCD-aware bijective swizzle (2752 % 8 == 0); bm fast => bn-groups share W panel
  const int wg  = (blockIdx.x & 7) * (GNWG >> 3) + (blockIdx.x >> 3);
  const int bm  = wg & 31;
  const int bn  = wg >> 5;
  const int row0 = bm * 128;
  const int col0 = bn * 128;

  // staging: 512 16B-slots per tile; slot s = (row = s>>2, kslot = s&3)
  // instr j covers slots j*256 + t; per-wave LDS base is uniform (wid,j only)
  auto stage = [&](int kt, int buf) {
    #pragma unroll
    for (int j = 0; j < 2; ++j) {
      const int s  = j * 256 + t;
      const int r  = s >> 2;
      const int ks = s & 3;
      const unsigned short* ga = Xb + (size_t)(row0 + r) * KDIM + kt * 32 + ks * 8;
      const unsigned short* gb = Wb + (size_t)(col0 + r) * KDIM + kt * 32 + ks * 8;
      unsigned short* la = &As[buf][(j * 256 + wid * 64) * 8];
      unsigned short* lb = &Bs[buf][(j * 256 + wid * 64) * 8];
      __builtin_amdgcn_global_load_lds(
          (const __attribute__((address_space(1))) unsigned int*)ga,
          (__attribute__((address_space(3))) unsigned int*)la, 16, 0, 0);
      __builtin_amdgcn_global_load_lds(
          (const __attribute__((address_space(1))) unsigned int*)gb,
          (__attribute__((address_space(3))) unsigned int*)lb, 16, 0, 0);
    }
  };

  f32x4 acc[4][4];
  #pragma unroll
  for (int i = 0; i < 4; ++i)
    #pragma unroll
    for (int j = 0; j < 4; ++j)
      #pragma unroll
      for (int e = 0; e < 4; ++e)
        acc[i][j][e] = 0.0f;

  auto compute = [&](int buf) {
    bf16x8 a[4], b[4];
    #pragma unroll
    for (int mi = 0; mi < 4; ++mi)
      a[mi] = *(const bf16x8*)&As[buf][(wm * 64 + mi * 16 + lr) * 32 + kg * 8];
    #pragma unroll
    for (int ni = 0; ni < 4; ++ni)
      b[ni] = *(const bf16x8*)&Bs[buf][(wn * 64 + ni * 16 + lr) * 32 + kg * 8];
    #pragma unroll
    for (int mi = 0; mi < 4; ++mi)
      #pragma unroll
      for (int ni = 0; ni < 4; ++ni)
        acc[mi][ni] = __builtin_amdgcn_mfma_f32_16x16x32_bf16(
            a[mi], b[ni], acc[mi][ni], 0, 0, 0);
  };

  stage(0, 0);
  __syncthreads();

  for (int kt = 0; kt < KDIM / 32; kt += 2) {   // 128 K-steps, dbuf pairs
    if (kt + 1 < KDIM / 32) stage(kt + 1, 1);
    compute(0);
    __syncthreads();
    if (kt + 2 < KDIM / 32) stage(kt + 2, 0);
    compute(1);
    __syncthreads();
  }

  // epilogue: D layout col = lane&15, row = (lane>>4)*4 + j (m89)
  #pragma unroll
  for (int ni = 0; ni < 4; ++ni) {
    const int n = col0 + wn * 64 + ni * 16 + lr;
    const float sc = scale[n];
    const float bz = bias[n];
    #pragma unroll
    for (int mi = 0; mi < 4; ++mi) {
      const int m0 = row0 + wm * 64 + mi * 16 + (kg << 2);
      #pragma unroll
      for (int j = 0; j < 4; ++j)
        Out[(size_t)(m0 + j) * NDIM + n] = acc[mi][ni][j] * sc + bz;
    }
  }
}

// ---------------- fallback (round-1 fused kernel) if ws too small -----------

__global__ __launch_bounds__(256, 2)
void int4_linear_fused_kernel(const float* __restrict__ X,
                              const int* __restrict__ Wp,
                              const float* __restrict__ scale,
                              const float* __restrict__ bias,
                              float* __restrict__ Out)
{
  __shared__ alignas(16) unsigned short As[2][128][40];
  __shared__ alignas(16) unsigned short Bs[2][128][40];

  const int t    = threadIdx.x;
  const int lane = t & 63;
  const int wid  = t >> 6;
  const int wm   = wid >> 1;
  const int wn   = wid & 1;
  const int lr   = lane & 15;
  const int kg   = lane >> 4;

  const int NWG = GNWG;
  const int wg  = (blockIdx.x & 7) * (NWG >> 3) + (blockIdx.x >> 3);
  const int bm  = wg & 31;
  const int bn  = wg >> 5;
  const int row0 = bm * 128;
  const int col0 = bn * 128;

  const int arow = t >> 3;
  const int acol = (t & 7) << 2;
  const int brow  = t >> 1;
  const int bhalf = t & 1;

  const float* Abase = X  + (size_t)(row0 + arow) * KDIM + acol;
  const int*   Bbase = Wp + (size_t)(col0 + brow) * KP + (bhalf << 3);

  float4 aR[4];
  int4   bR[2];

  f32x4 acc[4][4];
  #pragma unroll
  for (int i = 0; i < 4; ++i)
    #pragma unroll
    for (int j = 0; j < 4; ++j)
      #pragma unroll
      for (int e = 0; e < 4; ++e)
        acc[i][j][e] = 0.0f;

  auto loadG = [&](int kt) {
    const float* ap = Abase + kt * 32;
    #pragma unroll
    for (int p = 0; p < 4; ++p)
      aR[p] = *(const float4*)(ap + (size_t)p * 32 * KDIM);
    const int* bp = Bbase + kt * 16;
    bR[0] = *(const int4*)bp;
    bR[1] = *(const int4*)(bp + 4);
  };

  auto stageL = [&](int buf) {
    #pragma unroll
    for (int p = 0; p < 4; ++p) {
      ushort4 u;
      u.x = f2bf(aR[p].x);
      u.y = f2bf(aR[p].y);
      u.z = f2bf(aR[p].z);
      u.w = f2bf(aR[p].w);
      *(ushort4*)&As[buf][arow + p * 32][acol] = u;
    }
    #pragma unroll
    for (int q = 0; q < 2; ++q) {
      const int vv[4] = {q ? bR[1].x : bR[0].x, q ? bR[1].y : bR[0].y,
                         q ? bR[1].z : bR[0].z, q ? bR[1].w : bR[0].w};
      u16x8 s;
      #pragma unroll
      for (int j = 0; j < 4; ++j) {
        const int lo = ((vv[j] & 15) ^ 8) - 8;
        const int hi = (((vv[j] >> 4) & 15) ^ 8) - 8;
        s[2 * j]     = f2bf((float)lo);
        s[2 * j + 1] = f2bf((float)hi);
      }
      *(u16x8*)&Bs[buf][brow][(bhalf << 4) + (q << 3)] = s;
    }
  };

  auto compute = [&](int buf) {
    bf16x8 a[4], b[4];
    #pragma unroll
    for (int mi = 0; mi < 4; ++mi)
      a[mi] = *(const bf16x8*)&As[buf][wm * 64 + mi * 16 + lr][kg * 8];
    #pragma unroll
    for (int ni = 0; ni < 4; ++ni)
      b[ni] = *(const bf16x8*)&Bs[buf][wn * 64 + ni * 16 + lr][kg * 8];
    #pragma unroll
    for (int mi = 0; mi < 4; ++mi)
      #pragma unroll
      for (int ni = 0; ni < 4; ++ni)
        acc[mi][ni] = __builtin_amdgcn_mfma_f32_16x16x32_bf16(
            a[mi], b[ni], acc[mi][ni], 0, 0, 0);
  };

  loadG(0);
  stageL(0);
  __syncthreads();

  for (int kt = 0; kt < KDIM / 32; ++kt) {
    const int cur = kt & 1;
    if (kt + 1 < KDIM / 32) loadG(kt + 1);
    compute(cur);
    if (kt + 1 < KDIM / 32) stageL(cur ^ 1);
    __syncthreads();
  }

  #pragma unroll
  for (int ni = 0; ni < 4; ++ni) {
    const int n = col0 + wn * 64 + ni * 16 + lr;
    const float sc = scale[n];
    const float bz = bias[n];
    #pragma unroll
    for (int mi = 0; mi < 4; ++mi) {
      const int m0 = row0 + wm * 64 + mi * 16 + (kg << 2);
      #pragma unroll
      for (int j = 0; j < 4; ++j)
        Out[(size_t)(m0 + j) * NDIM + n] = acc[mi][ni][j] * sc + bz;
    }
  }
}

// ---------------------------------------------------------------------------

extern "C" void kernel_launch(void* const* d_in, const int* in_sizes, int n_in,
                              void* d_out, int out_size, void* d_ws, size_t ws_size,
                              hipStream_t stream) {
  const float* x     = (const float*)d_in[0];
  const int*   wp    = (const int*)d_in[1];
  const float* scale = (const float*)d_in[2];
  const float* bias  = (const float*)d_in[3];
  float* out = (float*)d_out;

  const size_t need = ((size_t)MDIM * KDIM + (size_t)NDIM * KDIM) * 2;  // 118 MB

  if (ws_size >= need) {
    unsigned short* Xb = (unsigned short*)d_ws;
    unsigned short* Wb = Xb + (size_t)MDIM * KDIM;
    hipLaunchKernelGGL(cvt_x_kernel,    dim3(2048), dim3(256), 0, stream, x, Xb);
    hipLaunchKernelGGL(unpack_w_kernel, dim3(2048), dim3(256), 0, stream, wp, Wb);
    hipLaunchKernelGGL(gemm_bf16_kernel, dim3(GNWG), dim3(256), 0, stream,
                       Xb, Wb, scale, bias, out);
  } else {
    hipLaunchKernelGGL(int4_linear_fused_kernel, dim3(GNWG), dim3(256), 0, stream,
                       x, wp, scale, bias, out);
  }
}

// Round 9
// 687.490 us; speedup vs baseline: 1.4576x; 1.1059x over previous
//
#include <hip/hip_runtime.h>

typedef __attribute__((ext_vector_type(8))) short bf16x8;
typedef __attribute__((ext_vector_type(4))) float f32x4;
typedef __attribute__((ext_vector_type(8))) unsigned short u16x8;

#define MDIM 4096
#define NDIM 11008
#define KDIM 4096
#define KP   (KDIM / 2)

__device__ __forceinline__ unsigned short f2bf(float f) {
  unsigned int u = __float_as_uint(f);
  u += 0x7FFFu + ((u >> 16) & 1u);   // round-to-nearest-even
  return (unsigned short)(u >> 16);
}

// ---------------- prep kernels (memory-bound, ~42 us measured R7) ----------

__global__ __launch_bounds__(256) void cvt_x_kernel(const float* __restrict__ X,
                                                    unsigned short* __restrict__ Xb) {
  const int stride = gridDim.x * blockDim.x;
  for (int i = blockIdx.x * blockDim.x + threadIdx.x; i < (MDIM * KDIM / 8); i += stride) {
    const float4 f0 = ((const float4*)X)[2 * i];
    const float4 f1 = ((const float4*)X)[2 * i + 1];
    ushort4 a, b;
    a.x = f2bf(f0.x); a.y = f2bf(f0.y); a.z = f2bf(f0.z); a.w = f2bf(f0.w);
    b.x = f2bf(f1.x); b.y = f2bf(f1.y); b.z = f2bf(f1.z); b.w = f2bf(f1.w);
    ((ushort4*)Xb)[2 * i]     = a;
    ((ushort4*)Xb)[2 * i + 1] = b;
  }
}

__global__ __launch_bounds__(256) void unpack_w_kernel(const int* __restrict__ Wp,
                                                       unsigned short* __restrict__ Wb) {
  const int stride = gridDim.x * blockDim.x;
  const int n4 = NDIM * KP / 4;     // 5636096 int4-vectors
  for (int i = blockIdx.x * blockDim.x + threadIdx.x; i < n4; i += stride) {
    const int4 v = ((const int4*)Wp)[i];
    const int vv[4] = {v.x, v.y, v.z, v.w};
    u16x8 s;
    #pragma unroll
    for (int j = 0; j < 4; ++j) {
      const int lo = ((vv[j] & 15) ^ 8) - 8;          // sign-extend int4 (exact in bf16)
      const int hi = (((vv[j] >> 4) & 15) ^ 8) - 8;
      s[2 * j]     = f2bf((float)lo);
      s[2 * j + 1] = f2bf((float)hi);
    }
    *(u16x8*)(Wb + 8 * (size_t)i) = s;
  }
}

// ---------- R8 GEMM: 256x128 tile, BK=64, 3-buffer dist-2 counted-vmcnt -----
// Per buf: A 256x64 (32KB) + B 128x64 (16KB) = 48KB; x3 bufs = 144KB dynamic LDS.
// 8 waves as 4M x 2N -> 64x64 per wave, acc[4][4], 32 MFMA / K-tile / wave.
// Staging: 6 gload_lds(16B)/thread/tile; boundary wait vmcnt(6) keeps the
// prefetched tile's loads in flight across s_barrier (never drains to 0).
// LDS slot swizzle: 16B-slot ^= (row&7), applied on BOTH global source and
// ds_read (rule 21) -> ds_read_b128 at its 8-deep bank floor (was 16-way).

#define BM2 256
#define BN2 128
#define NT2 (KDIM / 64)                 // 64 K-tiles
#define NWG2 ((MDIM / BM2) * (NDIM / BN2))   // 16 * 86 = 1376
#define BUFSZ 24576                     // shorts per buf: A 16384 + B 8192
#define LDSB  (3 * BUFSZ * 2)           // 147456 bytes

__global__ __launch_bounds__(512, 1)
void gemm_bf16_256_kernel(const unsigned short* __restrict__ Xb,
                          const unsigned short* __restrict__ Wb,
                          const float* __restrict__ scale,
                          const float* __restrict__ bias,
                          float* __restrict__ Out) {
  extern __shared__ unsigned short lds[];

  const int t    = threadIdx.x;
  const int lane = t & 63;
  const int wid  = t >> 6;         // 0..7
  const int wr   = wid >> 1;       // 4 waves in M -> 64 rows each
  const int wc   = wid & 1;        // 2 waves in N -> 64 cols each
  const int lr   = lane & 15;
  const int kg   = lane >> 4;

  // XCD bijective swizzle (1376 % 8 == 0); bm fast => groups of 16 share W-panel
  const int wg   = (blockIdx.x & 7) * (NWG2 >> 3) + (blockIdx.x >> 3);
  const int bm   = wg & 15;
  const int bn   = wg >> 4;
  const int row0 = bm * BM2;
  const int col0 = bn * BN2;

  // staging: slot s -> row = s>>3, kslot = s&7 (16B slots, 8 per 128B row).
  // LDS dest is LINEAR (s*16B); global source uses kslot^(row&7) pre-swizzle.
  auto stage = [&](int kt, int buf) {
    unsigned short* Ab = lds + buf * BUFSZ;
    unsigned short* Bb = Ab + 16384;
    #pragma unroll
    for (int p = 0; p < 4; ++p) {                    // A: 2048 slots
      const int s  = p * 512 + t;
      const int r  = s >> 3;
      const int ks = (s & 7) ^ (r & 7);
      const unsigned short* ga = Xb + (size_t)(row0 + r) * KDIM + kt * 64 + ks * 8;
      unsigned short* la = Ab + (p * 512 + wid * 64) * 8;   // wave-uniform base
      __builtin_amdgcn_global_load_lds(
          (const __attribute__((address_space(1))) unsigned int*)ga,
          (__attribute__((address_space(3))) unsigned int*)la, 16, 0, 0);
    }
    #pragma unroll
    for (int p = 0; p < 2; ++p) {                    // B: 1024 slots
      const int s  = p * 512 + t;
      const int r  = s >> 3;
      const int ks = (s & 7) ^ (r & 7);
      const unsigned short* gb = Wb + (size_t)(col0 + r) * KDIM + kt * 64 + ks * 8;
      unsigned short* lb = Bb + (p * 512 + wid * 64) * 8;
      __builtin_amdgcn_global_load_lds(
          (const __attribute__((address_space(1))) unsigned int*)gb,
          (__attribute__((address_space(3))) unsigned int*)lb, 16, 0, 0);
    }
  };

  f32x4 acc[4][4];
  #pragma unroll
  for (int i = 0; i < 4; ++i)
    #pragma unroll
    for (int j = 0; j < 4; ++j)
      #pragma unroll
      for (int e = 0; e < 4; ++e)
        acc[i][j][e] = 0.0f;

  auto compute = [&](int buf) {
    const unsigned short* Ab = lds + buf * BUFSZ;
    const unsigned short* Bb = Ab + 16384;
    #pragma unroll
    for (int ks = 0; ks < 2; ++ks) {                 // two 32-wide k-slices
      bf16x8 a[4], b[4];
      #pragma unroll
      for (int mi = 0; mi < 4; ++mi) {
        const int r  = wr * 64 + mi * 16 + lr;
        const int sl = (ks * 4 + kg) ^ (r & 7);
        a[mi] = *(const bf16x8*)&Ab[r * 64 + sl * 8];
      }
      #pragma unroll
      for (int ni = 0; ni < 4; ++ni) {
        const int r  = wc * 64 + ni * 16 + lr;
        const int sl = (ks * 4 + kg) ^ (r & 7);
        b[ni] = *(const bf16x8*)&Bb[r * 64 + sl * 8];
      }
      #pragma unroll
      for (int mi = 0; mi < 4; ++mi)
        #pragma unroll
        for (int ni = 0; ni < 4; ++ni)
          acc[mi][ni] = __builtin_amdgcn_mfma_f32_16x16x32_bf16(
              a[mi], b[ni], acc[mi][ni], 0, 0, 0);
    }
  };

  // Prologue: stage tiles 0,1 (12 loads); wait tile 0 (leave tile 1 flying).
  stage(0, 0);
  stage(1, 1);
  asm volatile("s_waitcnt vmcnt(6)" ::: "memory");
  __builtin_amdgcn_s_barrier();

  int buf = 0;
  for (int kt = 0; kt < NT2; ++kt) {
    if (kt + 2 < NT2) {
      int b2 = buf + 2; if (b2 >= 3) b2 -= 3;
      stage(kt + 2, b2);                 // writes the buffer compute freed last iter
    }
    compute(buf);
    if (kt == NT2 - 1) break;
    // boundary: per-wave wait for next tile's loads (oldest 6 of 12), then join.
    if (kt + 2 < NT2) {
      asm volatile("s_waitcnt vmcnt(6)" ::: "memory");
    } else {
      asm volatile("s_waitcnt vmcnt(0)" ::: "memory");
    }
    __builtin_amdgcn_s_barrier();
    ++buf; if (buf == 3) buf = 0;
  }

  // epilogue: D layout col = lane&15, row = (lane>>4)*4 + j (m89)
  #pragma unroll
  for (int ni = 0; ni < 4; ++ni) {
    const int n = col0 + wc * 64 + ni * 16 + lr;
    const float sc = scale[n];
    const float bz = bias[n];
    #pragma unroll
    for (int mi = 0; mi < 4; ++mi) {
      const int m0 = row0 + wr * 64 + mi * 16 + (kg << 2);
      #pragma unroll
      for (int j = 0; j < 4; ++j)
        Out[(size_t)(m0 + j) * NDIM + n] = acc[mi][ni][j] * sc + bz;
    }
  }
}

// ---------------- R7 GEMM kept as fallback (proven 524 us) ------------------

#define GNWG ((MDIM / 128) * (NDIM / 128))   // 2752

__global__ __launch_bounds__(256, 2)
void gemm_bf16_kernel(const unsigned short* __restrict__ Xb,
                      const unsigned short* __restrict__ Wb,
                      const float* __restrict__ scale,
                      const float* __restrict__ bias,
                      float* __restrict__ Out) {
  __shared__ alignas(16) unsigned short As[2][128 * 32];
  __shared__ alignas(16) unsigned short Bs[2][128 * 32];

  const int t    = threadIdx.x;
  const int lane = t & 63;
  const int wid  = t >> 6;
  const int wm   = wid >> 1;
  const int wn   = wid & 1;
  const int lr   = lane & 15;
  const int kg   = lane >> 4;

  const int wg  = (blockIdx.x & 7) * (GNWG >> 3) + (blockIdx.x >> 3);
  const int bm  = wg & 31;
  const int bn  = wg >> 5;
  const int row0 = bm * 128;
  const int col0 = bn * 128;

  auto stage = [&](int kt, int buf) {
    #pragma unroll
    for (int j = 0; j < 2; ++j) {
      const int s  = j * 256 + t;
      const int r  = s >> 2;
      const int ks = s & 3;
      const unsigned short* ga = Xb + (size_t)(row0 + r) * KDIM + kt * 32 + ks * 8;
      const unsigned short* gb = Wb + (size_t)(col0 + r) * KDIM + kt * 32 + ks * 8;
      unsigned short* la = &As[buf][(j * 256 + wid * 64) * 8];
      unsigned short* lb = &Bs[buf][(j * 256 + wid * 64) * 8];
      __builtin_amdgcn_global_load_lds(
          (const __attribute__((address_space(1))) unsigned int*)ga,
          (__attribute__((address_space(3))) unsigned int*)la, 16, 0, 0);
      __builtin_amdgcn_global_load_lds(
          (const __attribute__((address_space(1))) unsigned int*)gb,
          (__attribute__((address_space(3))) unsigned int*)lb, 16, 0, 0);
    }
  };

  f32x4 acc[4][4];
  #pragma unroll
  for (int i = 0; i < 4; ++i)
    #pragma unroll
    for (int j = 0; j < 4; ++j)
      #pragma unroll
      for (int e = 0; e < 4; ++e)
        acc[i][j][e] = 0.0f;

  auto compute = [&](int buf) {
    bf16x8 a[4], b[4];
    #pragma unroll
    for (int mi = 0; mi < 4; ++mi)
      a[mi] = *(const bf16x8*)&As[buf][(wm * 64 + mi * 16 + lr) * 32 + kg * 8];
    #pragma unroll
    for (int ni = 0; ni < 4; ++ni)
      b[ni] = *(const bf16x8*)&Bs[buf][(wn * 64 + ni * 16 + lr) * 32 + kg * 8];
    #pragma unroll
    for (int mi = 0; mi < 4; ++mi)
      #pragma unroll
      for (int ni = 0; ni < 4; ++ni)
        acc[mi][ni] = __builtin_amdgcn_mfma_f32_16x16x32_bf16(
            a[mi], b[ni], acc[mi][ni], 0, 0, 0);
  };

  stage(0, 0);
  __syncthreads();

  for (int kt = 0; kt < KDIM / 32; kt += 2) {
    if (kt + 1 < KDIM / 32) stage(kt + 1, 1);
    compute(0);
    __syncthreads();
    if (kt + 2 < KDIM / 32) stage(kt + 2, 0);
    compute(1);
    __syncthreads();
  }

  #pragma unroll
  for (int ni = 0; ni < 4; ++ni) {
    const int n = col0 + wn * 64 + ni * 16 + lr;
    const float sc = scale[n];
    const float bz = bias[n];
    #pragma unroll
    for (int mi = 0; mi < 4; ++mi) {
      const int m0 = row0 + wm * 64 + mi * 16 + (kg << 2);
      #pragma unroll
      for (int j = 0; j < 4; ++j)
        Out[(size_t)(m0 + j) * NDIM + n] = acc[mi][ni][j] * sc + bz;
    }
  }
}

// ---------------- fallback (round-1 fused kernel) if ws too small -----------

__global__ __launch_bounds__(256, 2)
void int4_linear_fused_kernel(const float* __restrict__ X,
                              const int* __restrict__ Wp,
                              const float* __restrict__ scale,
                              const float* __restrict__ bias,
                              float* __restrict__ Out)
{
  __shared__ alignas(16) unsigned short As[2][128][40];
  __shared__ alignas(16) unsigned short Bs[2][128][40];

  const int t    = threadIdx.x;
  const int lane = t & 63;
  const int wid  = t >> 6;
  const int wm   = wid >> 1;
  const int wn   = wid & 1;
  const int lr   = lane & 15;
  const int kg   = lane >> 4;

  const int wg  = (blockIdx.x & 7) * (GNWG >> 3) + (blockIdx.x >> 3);
  const int bm  = wg & 31;
  const int bn  = wg >> 5;
  const int row0 = bm * 128;
  const int col0 = bn * 128;

  const int arow = t >> 3;
  const int acol = (t & 7) << 2;
  const int brow  = t >> 1;
  const int bhalf = t & 1;

  const float* Abase = X  + (size_t)(row0 + arow) * KDIM + acol;
  const int*   Bbase = Wp + (size_t)(col0 + brow) * KP + (bhalf << 3);

  float4 aR[4];
  int4   bR[2];

  f32x4 acc[4][4];
  #pragma unroll
  for (int i = 0; i < 4; ++i)
    #pragma unroll
    for (int j = 0; j < 4; ++j)
      #pragma unroll
      for (int e = 0; e < 4; ++e)
        acc[i][j][e] = 0.0f;

  auto loadG = [&](int kt) {
    const float* ap = Abase + kt * 32;
    #pragma unroll
    for (int p = 0; p < 4; ++p)
      aR[p] = *(const float4*)(ap + (size_t)p * 32 * KDIM);
    const int* bp = Bbase + kt * 16;
    bR[0] = *(const int4*)bp;
    bR[1] = *(const int4*)(bp + 4);
  };

  auto stageL = [&](int buf) {
    #pragma unroll
    for (int p = 0; p < 4; ++p) {
      ushort4 u;
      u.x = f2bf(aR[p].x);
      u.y = f2bf(aR[p].y);
      u.z = f2bf(aR[p].z);
      u.w = f2bf(aR[p].w);
      *(ushort4*)&As[buf][arow + p * 32][acol] = u;
    }
    #pragma unroll
    for (int q = 0; q < 2; ++q) {
      const int vv[4] = {q ? bR[1].x : bR[0].x, q ? bR[1].y : bR[0].y,
                         q ? bR[1].z : bR[0].z, q ? bR[1].w : bR[0].w};
      u16x8 s;
      #pragma unroll
      for (int j = 0; j < 4; ++j) {
        const int lo = ((vv[j] & 15) ^ 8) - 8;
        const int hi = (((vv[j] >> 4) & 15) ^ 8) - 8;
        s[2 * j]     = f2bf((float)lo);
        s[2 * j + 1] = f2bf((float)hi);
      }
      *(u16x8*)&Bs[buf][brow][(bhalf << 4) + (q << 3)] = s;
    }
  };

  auto compute = [&](int buf) {
    bf16x8 a[4], b[4];
    #pragma unroll
    for (int mi = 0; mi < 4; ++mi)
      a[mi] = *(const bf16x8*)&As[buf][wm * 64 + mi * 16 + lr][kg * 8];
    #pragma unroll
    for (int ni = 0; ni < 4; ++ni)
      b[ni] = *(const bf16x8*)&Bs[buf][wn * 64 + ni * 16 + lr][kg * 8];
    #pragma unroll
    for (int mi = 0; mi < 4; ++mi)
      #pragma unroll
      for (int ni = 0; ni < 4; ++ni)
        acc[mi][ni] = __builtin_amdgcn_mfma_f32_16x16x32_bf16(
            a[mi], b[ni], acc[mi][ni], 0, 0, 0);
  };

  loadG(0);
  stageL(0);
  __syncthreads();

  for (int kt = 0; kt < KDIM / 32; ++kt) {
    const int cur = kt & 1;
    if (kt + 1 < KDIM / 32) loadG(kt + 1);
    compute(cur);
    if (kt + 1 < KDIM / 32) stageL(cur ^ 1);
    __syncthreads();
  }

  #pragma unroll
  for (int ni = 0; ni < 4; ++ni) {
    const int n = col0 + wn * 64 + ni * 16 + lr;
    const float sc = scale[n];
    const float bz = bias[n];
    #pragma unroll
    for (int mi = 0; mi < 4; ++mi) {
      const int m0 = row0 + wm * 64 + mi * 16 + (kg << 2);
      #pragma unroll
      for (int j = 0; j < 4; ++j)
        Out[(size_t)(m0 + j) * NDIM + n] = acc[mi][ni][j] * sc + bz;
    }
  }
}

// ---------------------------------------------------------------------------

extern "C" void kernel_launch(void* const* d_in, const int* in_sizes, int n_in,
                              void* d_out, int out_size, void* d_ws, size_t ws_size,
                              hipStream_t stream) {
  const float* x     = (const float*)d_in[0];
  const int*   wp    = (const int*)d_in[1];
  const float* scale = (const float*)d_in[2];
  const float* bias  = (const float*)d_in[3];
  float* out = (float*)d_out;

  const size_t need = ((size_t)MDIM * KDIM + (size_t)NDIM * KDIM) * 2;  // 118 MB

  if (ws_size >= need) {
    unsigned short* Xb = (unsigned short*)d_ws;
    unsigned short* Wb = Xb + (size_t)MDIM * KDIM;
    hipLaunchKernelGGL(cvt_x_kernel,    dim3(2048), dim3(256), 0, stream, x, Xb);
    hipLaunchKernelGGL(unpack_w_kernel, dim3(2048), dim3(256), 0, stream, wp, Wb);

    hipError_t attr_ok = hipFuncSetAttribute(
        (const void*)gemm_bf16_256_kernel,
        hipFuncAttributeMaxDynamicSharedMemorySize, LDSB);
    if (attr_ok == hipSuccess) {
      hipLaunchKernelGGL(gemm_bf16_256_kernel, dim3(NWG2), dim3(512), LDSB, stream,
                         Xb, Wb, scale, bias, out);
    } else {
      hipLaunchKernelGGL(gemm_bf16_kernel, dim3(GNWG), dim3(256), 0, stream,
                         Xb, Wb, scale, bias, out);
    }
  } else {
    hipLaunchKernelGGL(int4_linear_fused_kernel, dim3(GNWG), dim3(256), 0, stream,
                       x, wp, scale, bias, out);
  }
}